// Round 2
// baseline (1081.789 us; speedup 1.0000x reference)
//
#include <hip/hip_runtime.h>
#include <math.h>

// SoftSkeletonize via the erosion-chain identity:
//   e_0 = img, e_{i+1} = erode(e_i)      (erode = 5-pt cross min, +inf pad)
//   delta_i = relu(e_i - dilate3x3(e_{i+1}))            (dilate pad = -inf)
//   skel: s = delta_0; s += relu(delta_i - s*delta_i), i = 1..40
//
// 5 fused phases (S = 9,8,8,8,8 chain steps). Per 64x64 tile, stage e with
// halo (11 rows / 12 cols) in LDS; S+1 merged passes per phase.
//
// Round-6 changes vs round-5 (956 us): the remaining SQ_LDS_BANK_CONFLICT
// (2.65e7) is ~4 cyc per LDS instruction uniformly = intrinsic b128 datapath
// overhead (m134: 12 vs 8 cyc), NOT a layout problem. Only fix: fewer LDS
// instructions. Of the 10 b128 loads per central thread-pass, 8 were consumed
// as a SINGLE scalar (.w/.x horizontal edges) -- and those scalars live in
// the adjacent lane's registers (consecutive lanes = consecutive quad-cols).
//  * All 8 edge scalars now come from DPP lane shifts (row_shr:1/row_shl:1)
//    on register values: zero LDS traffic, 1 VALU op each.
//  * DPP is invalid across 16-lane rows: lanes 0/15 mod 16 preload the `old`
//    operand from LDS via exec-masked b32 reads (<=4 active lanes, ~free).
//  * DPP sources must be exec-on: all DPP at act-wide exec (do_dl guard is
//    wave-uniform). Final dilate-only pass (t=S+1, cw-exec) uses direct LDS
//    b32 edge reads instead (1 pass of 10).
//  * Lane-shift garbage at logical row wraps (c 21->0) lands in the >=12-col
//    margin (spreads <=1 col/pass x 10 passes), same tolerance as the stale
//    halo; all garbage finite or absorbed by IEEE fminf/fmaxf NaN rules.
// LDS per thread-pass: 10 b128 reads + 2 writes -> 2 b128 reads + 2 writes.
// LDS: 2 x 86 x 92 x 4B = 63.3 KB (< 64 KB static limit, 2 blocks/CU).

#define HH 1024
#define WW 1024
#define T 64
#define MTR 11                 // top row margin  (central rows start at buf row 11)
#define MTC 12                 // left col margin (central cols start at quad 3)
#define RH 86                  // buffer rows
#define STq 22                 // worker quad-cols per row
#define STGQ 23                // staged quads per row (fills the 92-float row)
#define STRD 92                // floats per buffer row (23 quads -> conflict-free b128)
#define NT 512
#define NIDX 924               // 42 row-pairs x 22 quad-cols

#define DPP_SHR1 0x111         // dest lane i = src lane i-1 (left neighbor)
#define DPP_SHL1 0x101         // dest lane i = src lane i+1 (right neighbor)

#define LD4(p)    (*(const float4*)(p))
#define ST4(p, v) (*(float4*)(p) = (v))

template<int CTRL>
__device__ __forceinline__ float dppf(float old, float x) {
    return __int_as_float(__builtin_amdgcn_update_dpp(
        __float_as_int(old), __float_as_int(x), CTRL, 0xF, 0xF, false));
}

__device__ __forceinline__ float relu_(float x) { return x > 0.f ? x : 0.f; }
__device__ __forceinline__ float4 min4_(float4 a, float4 b) {
    return make_float4(fminf(a.x,b.x), fminf(a.y,b.y), fminf(a.z,b.z), fminf(a.w,b.w));
}
__device__ __forceinline__ float4 max4_(float4 a, float4 b) {
    return make_float4(fmaxf(a.x,b.x), fmaxf(a.y,b.y), fmaxf(a.z,b.z), fmaxf(a.w,b.w));
}
// 3-tap horizontal min/max of quad a with scalar edges L (col-1), R (col+4)
__device__ __forceinline__ float4 hmin4(float L, float4 a, float R) {
    float4 h;
    h.x = fminf(L,   fminf(a.x, a.y)); h.y = fminf(a.x, fminf(a.y, a.z));
    h.z = fminf(a.y, fminf(a.z, a.w)); h.w = fminf(a.z, fminf(a.w, R));
    return h;
}
__device__ __forceinline__ float4 hmax4(float L, float4 a, float R) {
    float4 h;
    h.x = fmaxf(L,   fmaxf(a.x, a.y)); h.y = fmaxf(a.x, fmaxf(a.y, a.z));
    h.z = fmaxf(a.y, fmaxf(a.z, a.w)); h.w = fmaxf(a.z, fmaxf(a.w, R));
    return h;
}
__device__ __forceinline__ float4 dmask4(float4 v, float rm, float4 cm) {
    float4 o;
    o.x = fminf(fminf(v.x, cm.x), rm); o.y = fminf(fminf(v.y, cm.y), rm);
    o.z = fminf(fminf(v.z, cm.z), rm); o.w = fminf(fminf(v.w, cm.w), rm);
    return o;
}
__device__ __forceinline__ void skup(float4& s, float4 e, float4 d, bool init) {
    float4 dl;
    dl.x = relu_(e.x - d.x); dl.y = relu_(e.y - d.y);
    dl.z = relu_(e.z - d.z); dl.w = relu_(e.w - d.w);
    if (init) { s = dl; }
    else {
        s.x += relu_(dl.x - s.x * dl.x); s.y += relu_(dl.y - s.y * dl.y);
        s.z += relu_(dl.z - s.z * dl.z); s.w += relu_(dl.w - s.w * dl.w);
    }
}

__global__ __launch_bounds__(NT, 4) void phase_kernel(
    const float* __restrict__ src, float* __restrict__ dst,
    float* __restrict__ skel, int S, int first, int last)
{
    __shared__ __align__(16) float buf0[RH * STRD + 4];
    __shared__ __align__(16) float buf1[RH * STRD + 4];

    const int h0 = blockIdx.y * T;
    const int w0 = blockIdx.x * T;
    const size_t plane = (size_t)HH * WW;
    const float* sp = src + blockIdx.z * plane;
    float* skp = skel + blockIdx.z * plane;
    float* dp = dst ? dst + blockIdx.z * plane : nullptr;

    const int tid = threadIdx.x;
    const bool border = (h0 == 0) || (w0 == 0) || (h0 + T == HH) || (w0 + T == WW);

    // ---- stage e_{i0} (+inf outside image) into buf0
    if (!border) {
        const float* base = sp + (size_t)(h0 - MTR) * WW + (w0 - MTC);
        for (int i = tid; i < RH * STGQ; i += NT) {
            int r = i / STGQ, q = i - r * STGQ;
            ST4(&buf0[r * STRD + 4 * q], LD4(base + (size_t)r * WW + 4 * q));
        }
    } else {
        for (int i = tid; i < RH * STRD; i += NT) {
            int r = i / STRD, c = i - r * STRD;
            int gh = h0 - MTR + r, gw = w0 - MTC + c;
            float v = INFINITY;
            if ((unsigned)gh < HH && (unsigned)gw < WW) v = sp[(size_t)gh * WW + gw];
            buf0[r * STRD + c] = v;
        }
    }

    // ---- per-round geometry (round q handles idx = tid + NT*q)
    int pq[2], cq[2], oq[2];
    bool act[2], cen[2];
    float4 s0[2], s1[2];
    float4 a0r[2], a1r[2];   // e_{t-1} at own 2 rows (register-resident)
    float4 ep0[2], ep1[2];   // e_{t-2} at own 2 rows (register-resident)
    const float4 z4 = make_float4(0.f, 0.f, 0.f, 0.f);
#pragma unroll
    for (int q = 0; q < 2; ++q) {
        int idx = tid + NT * q;
        act[q] = (idx < NIDX);
        int p = idx / STq, c = idx - STq * p;
        pq[q] = p; cq[q] = c;
        oq[q] = act[q] ? (1 + 2 * p) * STRD + 4 * c : STRD;  // clamp inactive
        cen[q] = act[q] && (p >= 5) && (p <= 36) && (c >= 3) && (c <= 18);
        a0r[q] = z4; a1r[q] = z4; ep0[q] = z4; ep1[q] = z4;   // defined for DPP
    }
    if (!first) {
#pragma unroll
        for (int q = 0; q < 2; ++q) if (cen[q]) {
            const float* g = skp + (size_t)(h0 + 2 * pq[q] - 10) * WW + (w0 + 4 * cq[q] - 12);
            s0[q] = LD4(g); s1[q] = LD4(g + WW);
        }
    }
    __syncthreads();

    // ---- init register-resident own rows from staged e_{i0}
#pragma unroll
    for (int q = 0; q < 2; ++q) if (act[q]) {
        a0r[q] = LD4(buf0 + oq[q]);
        a1r[q] = LD4(buf0 + oq[q] + STRD);
    }

    const int lm = tid & 15;

    for (int t = 1; t <= S + 1; ++t) {
        float* sb = ((t - 1) & 1) ? buf1 : buf0;
        float* db = (t & 1) ? buf1 : buf0;
        const bool do_er = (t <= S);
        const bool do_dl = (t >= 2);
        const bool init = (first != 0) && (t == 2);
        if (do_er) {
#pragma unroll
            for (int q = 0; q < 2; ++q) {
                if (!act[q]) continue;
                const bool cw = cen[q] && do_dl;
                const int o = oq[q];
                // only 2 full-quad LDS reads per pass
                float4 U = LD4(sb + o - STRD);
                float4 D = LD4(sb + o + 2 * STRD);
                // DPP fallbacks for 16-lane row boundaries (<=4 active lanes each)
                float fL0 = 0.f, fL1 = 0.f, fLU = 0.f, fLD = 0.f;
                float fR0 = 0.f, fR1 = 0.f, fRU = 0.f, fRD = 0.f;
                if (lm == 0) {
                    fLU = sb[o - STRD - 1];     fL0 = sb[o - 1];
                    fL1 = sb[o + STRD - 1];     fLD = sb[o + 2 * STRD - 1];
                } else if (lm == 15) {
                    fRU = sb[o - STRD + 4];     fR0 = sb[o + 4];
                    fR1 = sb[o + STRD + 4];     fRD = sb[o + 2 * STRD + 4];
                }
                float4 A0 = a0r[q], A1 = a1r[q];
                // horizontal edge scalars via DPP lane shifts (act-wide exec)
                float eAm = dppf<DPP_SHR1>(fL0, A0.w);
                float eAp = dppf<DPP_SHL1>(fR0, A0.x);
                float eBm = dppf<DPP_SHR1>(fL1, A1.w);
                float eBp = dppf<DPP_SHL1>(fR1, A1.x);
                float eUm = 0.f, eUp = 0.f, eDm = 0.f, eDp = 0.f;
                if (do_dl) {   // wave-uniform -> exec stays act-wide
                    eUm = dppf<DPP_SHR1>(fLU, U.w);
                    eUp = dppf<DPP_SHL1>(fRU, U.x);
                    eDm = dppf<DPP_SHR1>(fLD, D.w);
                    eDp = dppf<DPP_SHL1>(fRD, D.x);
                }
                // erode
                float4 h0q = hmin4(eAm, A0, eAp);
                float4 h1q = hmin4(eBm, A1, eBp);
                float4 e0 = min4_(min4_(U, A1), h0q);
                float4 e1 = min4_(min4_(A0, D), h1q);
                if (border) {   // force +inf outside image
                    int ghb = h0 - MTR + 1 + 2 * pq[q];
                    int gwb = w0 - MTC + 4 * cq[q];
                    float4 cwm;
                    cwm.x = (unsigned)(gwb + 0) < WW ? -INFINITY : INFINITY;
                    cwm.y = (unsigned)(gwb + 1) < WW ? -INFINITY : INFINITY;
                    cwm.z = (unsigned)(gwb + 2) < WW ? -INFINITY : INFINITY;
                    cwm.w = (unsigned)(gwb + 3) < WW ? -INFINITY : INFINITY;
                    float r0 = (unsigned)ghb       < HH ? -INFINITY : INFINITY;
                    float r1 = (unsigned)(ghb + 1) < HH ? -INFINITY : INFINITY;
                    e0 = max4_(e0, max4_(make_float4(r0, r0, r0, r0), cwm));
                    e1 = max4_(e1, max4_(make_float4(r1, r1, r1, r1), cwm));
                }
                ST4(db + o, e0);
                ST4(db + o + STRD, e1);
                if (cw) {
                    float4 tU = U, tA = A0, tB = A1, tD = D;
                    float mUm = eUm, mUp = eUp, mAm = eAm, mAp = eAp;
                    float mBm = eBm, mBp = eBp, mDm = eDm, mDp = eDp;
                    if (border) {   // force -inf outside image before hmax
                        int ghb = h0 - MTR + 1 + 2 * pq[q];
                        int gwb = w0 - MTC + 4 * cq[q];
                        float rm0 = (unsigned)(ghb - 1) < HH ? INFINITY : -INFINITY;
                        float rm1 = (unsigned)(ghb)     < HH ? INFINITY : -INFINITY;
                        float rm2 = (unsigned)(ghb + 1) < HH ? INFINITY : -INFINITY;
                        float rm3 = (unsigned)(ghb + 2) < HH ? INFINITY : -INFINITY;
                        float cmL = (unsigned)(gwb - 1) < WW ? INFINITY : -INFINITY;
                        float cmR = (unsigned)(gwb + 4) < WW ? INFINITY : -INFINITY;
                        float4 cmC;
                        cmC.x = (unsigned)(gwb + 0) < WW ? INFINITY : -INFINITY;
                        cmC.y = (unsigned)(gwb + 1) < WW ? INFINITY : -INFINITY;
                        cmC.z = (unsigned)(gwb + 2) < WW ? INFINITY : -INFINITY;
                        cmC.w = (unsigned)(gwb + 3) < WW ? INFINITY : -INFINITY;
                        tU = dmask4(tU, rm0, cmC); tA = dmask4(tA, rm1, cmC);
                        tB = dmask4(tB, rm2, cmC); tD = dmask4(tD, rm3, cmC);
                        mUm = fminf(fminf(mUm, cmL), rm0); mUp = fminf(fminf(mUp, cmR), rm0);
                        mAm = fminf(fminf(mAm, cmL), rm1); mAp = fminf(fminf(mAp, cmR), rm1);
                        mBm = fminf(fminf(mBm, cmL), rm2); mBp = fminf(fminf(mBp, cmR), rm2);
                        mDm = fminf(fminf(mDm, cmL), rm3); mDp = fminf(fminf(mDp, cmR), rm3);
                    }
                    float4 hU = hmax4(mUm, tU, mUp);
                    float4 hA = hmax4(mAm, tA, mAp);
                    float4 hB = hmax4(mBm, tB, mBp);
                    float4 hD = hmax4(mDm, tD, mDp);
                    float4 d0 = max4_(hU, max4_(hA, hB));
                    float4 d1 = max4_(hA, max4_(hB, hD));
                    skup(s0[q], ep0[q], d0, init);
                    skup(s1[q], ep1[q], d1, init);
                }
                // rotate AFTER dilate/skup consumed e_{t-2}
                ep0[q] = A0; ep1[q] = A1;
                a0r[q] = e0; a1r[q] = e1;
            }
        } else {
            // t == S+1: dilate-only pass, cw-exec -> edges via direct LDS reads
#pragma unroll
            for (int q = 0; q < 2; ++q) {
                if (!cen[q]) continue;
                const int o = oq[q];
                float4 U = LD4(sb + o - STRD);
                float4 D = LD4(sb + o + 2 * STRD);
                float4 A0 = a0r[q], A1 = a1r[q];
                float mUm = sb[o - STRD - 1],     mUp = sb[o - STRD + 4];
                float mAm = sb[o - 1],            mAp = sb[o + 4];
                float mBm = sb[o + STRD - 1],     mBp = sb[o + STRD + 4];
                float mDm = sb[o + 2 * STRD - 1], mDp = sb[o + 2 * STRD + 4];
                float4 tU = U, tA = A0, tB = A1, tD = D;
                if (border) {
                    int ghb = h0 - MTR + 1 + 2 * pq[q];
                    int gwb = w0 - MTC + 4 * cq[q];
                    float rm0 = (unsigned)(ghb - 1) < HH ? INFINITY : -INFINITY;
                    float rm1 = (unsigned)(ghb)     < HH ? INFINITY : -INFINITY;
                    float rm2 = (unsigned)(ghb + 1) < HH ? INFINITY : -INFINITY;
                    float rm3 = (unsigned)(ghb + 2) < HH ? INFINITY : -INFINITY;
                    float cmL = (unsigned)(gwb - 1) < WW ? INFINITY : -INFINITY;
                    float cmR = (unsigned)(gwb + 4) < WW ? INFINITY : -INFINITY;
                    float4 cmC;
                    cmC.x = (unsigned)(gwb + 0) < WW ? INFINITY : -INFINITY;
                    cmC.y = (unsigned)(gwb + 1) < WW ? INFINITY : -INFINITY;
                    cmC.z = (unsigned)(gwb + 2) < WW ? INFINITY : -INFINITY;
                    cmC.w = (unsigned)(gwb + 3) < WW ? INFINITY : -INFINITY;
                    tU = dmask4(tU, rm0, cmC); tA = dmask4(tA, rm1, cmC);
                    tB = dmask4(tB, rm2, cmC); tD = dmask4(tD, rm3, cmC);
                    mUm = fminf(fminf(mUm, cmL), rm0); mUp = fminf(fminf(mUp, cmR), rm0);
                    mAm = fminf(fminf(mAm, cmL), rm1); mAp = fminf(fminf(mAp, cmR), rm1);
                    mBm = fminf(fminf(mBm, cmL), rm2); mBp = fminf(fminf(mBp, cmR), rm2);
                    mDm = fminf(fminf(mDm, cmL), rm3); mDp = fminf(fminf(mDp, cmR), rm3);
                }
                float4 hU = hmax4(mUm, tU, mUp);
                float4 hA = hmax4(mAm, tA, mAp);
                float4 hB = hmax4(mBm, tB, mBp);
                float4 hD = hmax4(mDm, tD, mDp);
                float4 d0 = max4_(hU, max4_(hA, hB));
                float4 d1 = max4_(hA, max4_(hB, hD));
                skup(s0[q], ep0[q], d0, init);
                skup(s1[q], ep1[q], d1, init);
            }
        }
        __syncthreads();
    }

    // ---- writeback: skel always; e_S central (from registers) if not last phase
#pragma unroll
    for (int q = 0; q < 2; ++q) if (cen[q]) {
        size_t grow = (size_t)(h0 + 2 * pq[q] - 10) * WW + (w0 + 4 * cq[q] - 12);
        ST4(skp + grow, s0[q]);
        ST4(skp + grow + WW, s1[q]);
        if (!last) {
            ST4(dp + grow, a0r[q]);
            ST4(dp + grow + WW, a1r[q]);
        }
    }
}

extern "C" void kernel_launch(void* const* d_in, const int* in_sizes, int n_in,
                              void* d_out, int out_size, void* d_ws, size_t ws_size,
                              hipStream_t stream) {
    const float* img = (const float*)d_in[0];
    float* skel = (float*)d_out;
    const int B = in_sizes[0] / (HH * WW);  // 16
    const size_t plane = (size_t)HH * WW;

    float* e0 = (float*)d_ws;
    float* e1 = e0 + (size_t)B * plane;

    dim3 grid(WW / T, HH / T, B);
    dim3 block(NT);

    const int Ks[5] = {9, 8, 8, 8, 8};   // 41 deltas total (init + 40 iters)
    const float* src = img;
    float* ebufs[2] = {e0, e1};
    for (int p = 0; p < 5; ++p) {
        int first = (p == 0), last = (p == 4);
        float* dstp = last ? nullptr : ebufs[p & 1];
        phase_kernel<<<grid, block, 0, stream>>>(src, dstp, skel, Ks[p], first, last);
        src = dstp;
    }
}